// Round 11
// baseline (113.858 us; speedup 1.0000x reference)
//
#include <hip/hip_runtime.h>
#include <hip/hip_bf16.h>

typedef unsigned short u16;
typedef unsigned int u32;
typedef unsigned long long u64;
typedef __attribute__((ext_vector_type(8))) short bf16x8;
typedef __attribute__((ext_vector_type(4))) float f32x4;
typedef __attribute__((ext_vector_type(4))) u16 u16x4;

#define N 4096
#define F 128
#define H 4
#define O 64
#define NW (N / 64)   // 64-bit words per adjacency row
#define NT 16         // KV tiles per column-half per z-slice (1024/64)
// log2(e)/8: folds the /sqrt(64) and the exp->exp2 conversion into Q.
#define QSCALE 0.18033688011112043f

__device__ inline float exp2_hw(float x) {
#if __has_builtin(__builtin_amdgcn_exp2f)
  return __builtin_amdgcn_exp2f(x);      // v_exp_f32, hazards handled by compiler
#else
  return __expf(x * 0.6931471805599453f);
#endif
}

__device__ inline u16 f2bf(float f) {           // RNE convert
  union { __hip_bfloat16 b; u16 u; } v;
  v.b = __float2bfloat16(f);
  return v.u;
}

// ---------------------------------------------------------------------------
// Fused prep: [0,1024) pack | [1024,1792) proj | [1792,1808) mask.
// ---------------------------------------------------------------------------
__global__ __launch_bounds__(256) void prep_kernel(
    const float* __restrict__ x, const float* __restrict__ adj,
    const float* __restrict__ wv, const float* __restrict__ wq,
    const float* __restrict__ wk, u16* __restrict__ Q, u16* __restrict__ K,
    u16* __restrict__ Vt, float* __restrict__ rmask, u64* __restrict__ bits) {
  const int b = blockIdx.x;
  const int t = threadIdx.x;

  if (b < 1024) {
    // ---- pack: adjacency (0/1 fp32) -> bitmask ----
    const int w = t >> 6, l = t & 63;
    const int row = b * 4 + w;
    const float* ar = adj + (size_t)row * N;
    u64* br = bits + (size_t)row * NW;
#pragma unroll 4
    for (int j2 = 0; j2 < 16; j2++) {
      float4 v = *(const float4*)&ar[j2 * 256 + l * 4];
      unsigned nib = (unsigned)(v.x != 0.f) | ((unsigned)(v.y != 0.f) << 1) |
                     ((unsigned)(v.z != 0.f) << 2) | ((unsigned)(v.w != 0.f) << 3);
      u64 word = (u64)nib << ((l & 15) * 4);
      word |= __shfl_xor(word, 1);
      word |= __shfl_xor(word, 2);
      word |= __shfl_xor(word, 4);
      word |= __shfl_xor(word, 8);
      if ((l & 15) == 0) br[j2 * 4 + (l >> 4)] = word;
    }
  } else if (b < 1792) {
    // ---- proj: fp32 GEMM, outputs bf16 (Q pre-scaled by QSCALE) ----
    __shared__ float xs[64][132];
    __shared__ float wsh[128][64];
    const int pb = b - 1024;
    const int brow = (pb & 63) * 64;
    const int p = pb >> 6, h = p / 3, which = p % 3;
    const float* W = (which == 0 ? wq : which == 1 ? wk : wv) + h * F * O;

#pragma unroll
    for (int i = 0; i < 8; i++) {
      int idx = t + i * 256, r = idx >> 5, c4 = idx & 31;
      *(float4*)&xs[r][c4 * 4] = *(const float4*)&x[(brow + r) * F + c4 * 4];
    }
#pragma unroll
    for (int i = 0; i < 8; i++) {
      int idx = t + i * 256, r = idx >> 4, c4 = idx & 15;
      *(float4*)&wsh[r][c4 * 4] = *(const float4*)&W[r * O + c4 * 4];
    }
    __syncthreads();

    const int r0 = (t >> 4) << 2, c0 = (t & 15) << 2;
    float acc[4][4] = {};
#pragma unroll 8
    for (int f = 0; f < F; f++) {
      float4 bb = *(float4*)&wsh[f][c0];
      float a0 = xs[r0 + 0][f], a1 = xs[r0 + 1][f];
      float a2 = xs[r0 + 2][f], a3 = xs[r0 + 3][f];
      acc[0][0] = fmaf(a0, bb.x, acc[0][0]); acc[0][1] = fmaf(a0, bb.y, acc[0][1]);
      acc[0][2] = fmaf(a0, bb.z, acc[0][2]); acc[0][3] = fmaf(a0, bb.w, acc[0][3]);
      acc[1][0] = fmaf(a1, bb.x, acc[1][0]); acc[1][1] = fmaf(a1, bb.y, acc[1][1]);
      acc[1][2] = fmaf(a1, bb.z, acc[1][2]); acc[1][3] = fmaf(a1, bb.w, acc[1][3]);
      acc[2][0] = fmaf(a2, bb.x, acc[2][0]); acc[2][1] = fmaf(a2, bb.y, acc[2][1]);
      acc[2][2] = fmaf(a2, bb.z, acc[2][2]); acc[2][3] = fmaf(a2, bb.w, acc[2][3]);
      acc[3][0] = fmaf(a3, bb.x, acc[3][0]); acc[3][1] = fmaf(a3, bb.y, acc[3][1]);
      acc[3][2] = fmaf(a3, bb.z, acc[3][2]); acc[3][3] = fmaf(a3, bb.w, acc[3][3]);
    }

    if (which == 0) {
      u16* dst = Q + h * N * O;
#pragma unroll
      for (int i = 0; i < 4; i++) {
        u16x4 v4 = { f2bf(acc[i][0] * QSCALE), f2bf(acc[i][1] * QSCALE),
                     f2bf(acc[i][2] * QSCALE), f2bf(acc[i][3] * QSCALE) };
        *(u16x4*)&dst[(brow + r0 + i) * O + c0] = v4;
      }
    } else if (which == 1) {
      u16* dst = K + h * N * O;
#pragma unroll
      for (int i = 0; i < 4; i++) {
        u16x4 v4 = { f2bf(acc[i][0]), f2bf(acc[i][1]), f2bf(acc[i][2]), f2bf(acc[i][3]) };
        *(u16x4*)&dst[(brow + r0 + i) * O + c0] = v4;
      }
    } else {
      u16* dst = Vt + h * O * N;  // transposed store: Vt[o][n]
#pragma unroll
      for (int j = 0; j < 4; j++) {
        u16x4 v4 = { f2bf(acc[0][j]), f2bf(acc[1][j]), f2bf(acc[2][j]), f2bf(acc[3][j]) };
        *(u16x4*)&dst[(c0 + j) * N + brow + r0] = v4;
      }
    }
  } else {
    // ---- mask: row_mask[n] = any(x[n][f] != 0) ----
    int n = (b - 1792) * 256 + t;
    const float4* xr = (const float4*)(x + n * F);
    float s = 0.f;
#pragma unroll
    for (int i = 0; i < F / 4; i++) {
      float4 v = xr[i];
      s += fabsf(v.x) + fabsf(v.y) + fabsf(v.z) + fabsf(v.w);
    }
    rmask[n] = (s != 0.f) ? 1.f : 0.f;
  }
}

// ---------------------------------------------------------------------------
// Fused masked attention. R5/R8-verified 8-wave geometry, z-split (NT=16).
// grid (N/64, H, 2), block 512 = 8 waves = 4 row-groups x 2 column-halves.
// K staged via global_load_lds (double-buffered, XOR-swizzled, rule #21);
// V read DIRECTLY from global (R2-R4-verified gather): the 4 rg-waves of an
// hc-half re-read the same 8KB half-tile within an iter -> L1-served; loads
// hoisted above softmax so L2 latency hides under the VALU block.
// LDS = kv 32KB + pst 16KB = 48KB. Q pre-scaled; P = 2^(leaky(s)).
// MFMA 16x16x32 bf16, C/D row=(l>>4)*4+r, col=l&15 (m89).
// ---------------------------------------------------------------------------
__global__ __launch_bounds__(512, 4) void attn_kernel(
    const u64* __restrict__ bits, const u16* __restrict__ Qg,
    const u16* __restrict__ Kg, const u16* __restrict__ Vtg,
    float* __restrict__ Opart, float* __restrict__ Spart) {
  __shared__ __align__(16) char kv[2][2][8192];   // [buf][K0,K1][64x128B]
  __shared__ __align__(16) u16 pst[8][16][64];    // per-wave P staging, swizzled

  const int tid = threadIdx.x;
  const int w = tid >> 6, l = tid & 63;
  const int lm = l & 15, lg = l >> 4;
  const int rg = w >> 1, hc = w & 1;     // row-group 0..3, column-half 0..1
  const int h = blockIdx.y;
  const int z = blockIdx.z;              // column slice 0..1 (2048 cols each)
  const int R0 = blockIdx.x * 64;
  const int WR0 = R0 + rg * 16;          // this wave's 16 Q-rows
  const int CB0 = z * 2048;              // this block's column base

  const char* Kb = (const char*)(Kg + h * N * O);    // 128B per key-row
  const u16* Vh = Vtg + (size_t)h * O * N;           // Vt[o][n] elements
  const u64* bblk = bits + (size_t)WR0 * NW;

  // staging geometry: lane fills LDS slot (row=w*8+(l>>3), col=(l&7)*16);
  // source is the INVERSE-swizzled global column (involution).
  const int srow = w * 8 + (l >> 3);                   // 0..63
  const int scol = ((l & 7) * 16) ^ ((srow & 7) << 4); // swizzled 16B chunk

  // Q fragments (held in regs): A[m=lm][k=lg*8+j]
  const u16* Qh = Qg + h * N * O;
  bf16x8 qa0 = *(const bf16x8*)&Qh[(WR0 + lm) * O + lg * 8];
  bf16x8 qa1 = *(const bf16x8*)&Qh[(WR0 + lm) * O + 32 + lg * 8];

  // pst addressing (byte offsets into this wave's 2KB slot), swizzled
  char* pbase = (char*)&pst[w][0][0];
  const char* prd0 = pbase + lm * 128 + ((lg * 16) ^ ((lm & 7) << 4));
  const char* prd1 = pbase + lm * 128 + ((64 + lg * 16) ^ ((lm & 7) << 4));

  f32x4 oacc[4];
  float lsum[4] = {0.f, 0.f, 0.f, 0.f};
#pragma unroll
  for (int i = 0; i < 4; i++) oacc[i] = (f32x4){0.f, 0.f, 0.f, 0.f};
  const f32x4 zero4 = {0.f, 0.f, 0.f, 0.f};

  auto STAGE = [&](int b, int t) {
    __builtin_amdgcn_global_load_lds(
        (const u32*)(Kb + (size_t)(CB0 + 0 * 1024 + t * 64 + srow) * 128 + scol),
        (u32*)&kv[b][0][w * 1024], 16, 0, 0);
    __builtin_amdgcn_global_load_lds(
        (const u32*)(Kb + (size_t)(CB0 + 1 * 1024 + t * 64 + srow) * 128 + scol),
        (u32*)&kv[b][1][w * 1024], 16, 0, 0);
  };

  STAGE(0, 0);
  __syncthreads();

  int b = 0;
#pragma unroll 1
  for (int t = 0; t < NT; ++t) {
    if (t + 1 < NT) STAGE(b ^ 1, t + 1);   // prefetch next K tile

    const int cb = CB0 + hc * 1024 + t * 64;     // this wave's 64-key base
    const int widx = cb >> 6;                    // 64-col word index

    // adjacency words (broadcast, L2-hot)
    u64 sh0 = bblk[(lg * 4 + 0) * NW + widx] >> lm;
    u64 sh1 = bblk[(lg * 4 + 1) * NW + widx] >> lm;
    u64 sh2 = bblk[(lg * 4 + 2) * NW + widx] >> lm;
    u64 sh3 = bblk[(lg * 4 + 3) * NW + widx] >> lm;

    // ---- S = Q K^T from staged K tile (swizzled reads) ----
    const char* Kt = &kv[b][hc][0];
    f32x4 sacc[4];
    __builtin_amdgcn_s_setprio(1);
#pragma unroll
    for (int tt = 0; tt < 4; tt++) {
      const int row = tt * 16 + lm;
      const int sw = (row & 7) << 4;
      bf16x8 kb0 = *(const bf16x8*)(Kt + row * 128 + ((lg * 16) ^ sw));
      bf16x8 kb1 = *(const bf16x8*)(Kt + row * 128 + ((lg * 16 + 64) ^ sw));
      f32x4 s0 = __builtin_amdgcn_mfma_f32_16x16x32_bf16(qa0, kb0, zero4, 0, 0, 0);
      sacc[tt] = __builtin_amdgcn_mfma_f32_16x16x32_bf16(qa1, kb1, s0, 0, 0, 0);
    }
    __builtin_amdgcn_s_setprio(0);

    // ---- V fragments: direct global gather (issued BEFORE softmax so L2
    // latency hides under the VALU block; 4 rg-waves share lines -> L1) ----
    bf16x8 vb[4][2];
#pragma unroll
    for (int ot = 0; ot < 4; ot++) {
      const size_t vrow = (size_t)(ot * 16 + lm) * N;
      vb[ot][0] = *(const bf16x8*)&Vh[vrow + cb + lg * 8];
      vb[ot][1] = *(const bf16x8*)&Vh[vrow + cb + 32 + lg * 8];
    }

    // ---- P = adj ? 2^(leaky(s)) : 0 ; stage bf16 P (swizzled) ----
#pragma unroll
    for (int tt = 0; tt < 4; tt++) {
#pragma unroll
      for (int r = 0; r < 4; r++) {
        u64 sh = (r == 0 ? sh0 : r == 1 ? sh1 : r == 2 ? sh2 : sh3);
        unsigned bit = (unsigned)(sh >> (tt * 16)) & 1u;
        float sv = sacc[tt][r];
        float lv = (sv < 0.f ? 0.2f * sv : sv);   // scaling folded into Q
        float p = bit ? exp2_hw(lv) : 0.f;
        lsum[r] += p;
        const int prow = lg * 4 + r;
        *(u16*)(pbase + prow * 128 +
                ((((tt * 16 + lm) * 2)) ^ ((prow & 7) << 4))) = f2bf(p);
      }
    }
    bf16x8 pa0 = *(const bf16x8*)prd0;
    bf16x8 pa1 = *(const bf16x8*)prd1;

    // ---- O += P V (B-frags from registers) ----
    __builtin_amdgcn_s_setprio(1);
#pragma unroll
    for (int ot = 0; ot < 4; ot++) {
      oacc[ot] = __builtin_amdgcn_mfma_f32_16x16x32_bf16(pa0, vb[ot][0], oacc[ot], 0, 0, 0);
      oacc[ot] = __builtin_amdgcn_mfma_f32_16x16x32_bf16(pa1, vb[ot][1], oacc[ot], 0, 0, 0);
    }
    __builtin_amdgcn_s_setprio(0);

    __syncthreads();   // drains K prefetch + protects buffer flip
    b ^= 1;
  }

  // ---- row-sum reduce across the 16 lm lanes ----
#pragma unroll
  for (int r = 0; r < 4; r++) {
    float s = lsum[r];
    s += __shfl_xor(s, 1);
    s += __shfl_xor(s, 2);
    s += __shfl_xor(s, 4);
    s += __shfl_xor(s, 8);
    lsum[r] = s;
  }

  // ---- merge the 2 column-halves in LDS (Om2 aliases kv = exactly 32KB;
  // barrier-safe). Wave row-sums parked raw in own pst slot (f32). ----
  float (*Om2)[64][64] = (float (*)[64][64])&kv[0][0][0];  // 32KB
#pragma unroll
  for (int ot = 0; ot < 4; ot++)
#pragma unroll
    for (int r = 0; r < 4; r++)
      Om2[hc][rg * 16 + lg * 4 + r][ot * 16 + lm] = oacc[ot][r];
  if (lm == 0) {
    float* ps = (float*)pbase;
#pragma unroll
    for (int r = 0; r < 4; r++) ps[lg * 4 + r] = lsum[r];
  }
  __syncthreads();

  // ---- write partials: Opart[z][h][row][col], Spart[z][h][row] ----
  const int row = tid >> 3;          // 0..63
  const int c0 = (tid & 7) * 8;      // 0..56
  const int grow = R0 + row;
  float* op = &Opart[(((size_t)z * H + h) * N + grow) * O + c0];
#pragma unroll
  for (int j = 0; j < 8; j++)
    op[j] = Om2[0][row][c0 + j] + Om2[1][row][c0 + j];
  if ((tid & 7) == 0) {
    const int rg2 = row >> 4, ri = row & 15;
    float s0 = ((float*)&pst[rg2 * 2 + 0][0][0])[ri];
    float s1 = ((float*)&pst[rg2 * 2 + 1][0][0])[ri];
    Spart[((size_t)z * H + h) * N + grow] = s0 + s1;
  }
}

// ---------------------------------------------------------------------------
// Merge the 2 z-slices: out = relu((O0+O1)/(S0+S1)) * rowmask.
// ---------------------------------------------------------------------------
__global__ __launch_bounds__(256) void merge_kernel(
    const float* __restrict__ Opart, const float* __restrict__ Spart,
    const float* __restrict__ rowmask, float* __restrict__ out) {
  const int h = blockIdx.y;
  const int idx = blockIdx.x * 256 + threadIdx.x;
  const int row = idx >> 4, c0 = (idx & 15) * 4;
  float S = Spart[(size_t)h * N + row] + Spart[((size_t)H + h) * N + row];
  float inv = (S > 0.f) ? 1.f / S : 0.f;
  float rm = rowmask[row];
  const float4 o0 = *(const float4*)&Opart[((size_t)h * N + row) * O + c0];
  const float4 o1 = *(const float4*)&Opart[(((size_t)H + h) * N + row) * O + c0];
  float4 r;
  r.x = fmaxf((o0.x + o1.x) * inv, 0.f) * rm;
  r.y = fmaxf((o0.y + o1.y) * inv, 0.f) * rm;
  r.z = fmaxf((o0.z + o1.z) * inv, 0.f) * rm;
  r.w = fmaxf((o0.w + o1.w) * inv, 0.f) * rm;
  *(float4*)&out[(size_t)row * (H * O) + h * O + c0] = r;
}

extern "C" void kernel_launch(void* const* d_in, const int* in_sizes, int n_in,
                              void* d_out, int out_size, void* d_ws, size_t ws_size,
                              hipStream_t stream) {
  const float* x   = (const float*)d_in[0];  // h [1,4096,128]
  const float* adj = (const float*)d_in[1];  // a [1,4096,4096]
  const float* wv  = (const float*)d_in[2];  // kernel      -> V
  const float* wq  = (const float*)d_in[3];  // attn_kernel -> Q (f_self)
  const float* wk  = (const float*)d_in[4];  // attn_kernel2-> K (f_other)
  float* out = (float*)d_out;

  u16* Q  = (u16*)d_ws;                     // [4][4096][64] bf16  (2 MB)
  u16* K  = Q + H * N * O;                  // [4][4096][64] bf16  (2 MB)
  u16* Vt = K + H * N * O;                  // [4][64][4096] bf16  (2 MB)
  float* rmask = (float*)(Vt + H * N * O);  // [4096] f32 (16 KB)
  u64* bits = (u64*)(rmask + N);            // [4096][64] u64 (2 MB)
  float* Opart = (float*)(bits + (size_t)N * NW);  // [2][4][4096][64] f32 (8 MB)
  float* Spart = Opart + (size_t)2 * H * N * O;    // [2][4][4096] f32 (128 KB)

  prep_kernel<<<dim3(1808), 256, 0, stream>>>(x, adj, wv, wq, wk, Q, K, Vt, rmask, bits);
  attn_kernel<<<dim3(N / 64, H, 2), 512, 0, stream>>>(bits, Q, K, Vt, Opart, Spart);
  merge_kernel<<<dim3(N * O / 4 / 256, H), 256, 0, stream>>>(Opart, Spart, rmask, out);
}

// Round 12
// 75.686 us; speedup vs baseline: 1.5044x; 1.5044x over previous
//
#include <hip/hip_runtime.h>
#include <hip/hip_bf16.h>

typedef unsigned short u16;
typedef unsigned int u32;
typedef unsigned long long u64;
typedef __attribute__((ext_vector_type(8))) short bf16x8;
typedef __attribute__((ext_vector_type(4))) float f32x4;
typedef __attribute__((ext_vector_type(4))) u16 u16x4;

#define N 4096
#define F 128
#define H 4
#define O 64
#define NW (N / 64)   // 64-bit words per adjacency row
#define NT 16         // KV tiles per column-half per z-slice (1024/64)
// log2(e)/8: folds the /sqrt(64) and the exp->exp2 conversion into Q.
#define QSCALE 0.18033688011112043f

__device__ inline float exp2_hw(float x) {
#if __has_builtin(__builtin_amdgcn_exp2f)
  return __builtin_amdgcn_exp2f(x);      // v_exp_f32, hazards handled by compiler
#else
  return __expf(x * 0.6931471805599453f);
#endif
}

__device__ inline u16 f2bf(float f) {           // RNE convert
  union { __hip_bfloat16 b; u16 u; } v;
  v.b = __float2bfloat16(f);
  return v.u;
}

// ---------------------------------------------------------------------------
// Fused prep: [0,1024) pack | [1024,1792) proj | [1792,1808) mask.
// ---------------------------------------------------------------------------
__global__ __launch_bounds__(256) void prep_kernel(
    const float* __restrict__ x, const float* __restrict__ adj,
    const float* __restrict__ wv, const float* __restrict__ wq,
    const float* __restrict__ wk, u16* __restrict__ Q, u16* __restrict__ K,
    u16* __restrict__ Vt, float* __restrict__ rmask, u64* __restrict__ bits) {
  const int b = blockIdx.x;
  const int t = threadIdx.x;

  if (b < 1024) {
    // ---- pack: adjacency (0/1 fp32) -> bitmask ----
    const int w = t >> 6, l = t & 63;
    const int row = b * 4 + w;
    const float* ar = adj + (size_t)row * N;
    u64* br = bits + (size_t)row * NW;
#pragma unroll 4
    for (int j2 = 0; j2 < 16; j2++) {
      float4 v = *(const float4*)&ar[j2 * 256 + l * 4];
      unsigned nib = (unsigned)(v.x != 0.f) | ((unsigned)(v.y != 0.f) << 1) |
                     ((unsigned)(v.z != 0.f) << 2) | ((unsigned)(v.w != 0.f) << 3);
      u64 word = (u64)nib << ((l & 15) * 4);
      word |= __shfl_xor(word, 1);
      word |= __shfl_xor(word, 2);
      word |= __shfl_xor(word, 4);
      word |= __shfl_xor(word, 8);
      if ((l & 15) == 0) br[j2 * 4 + (l >> 4)] = word;
    }
  } else if (b < 1792) {
    // ---- proj: fp32 GEMM, outputs bf16 (Q pre-scaled by QSCALE) ----
    __shared__ float xs[64][132];
    __shared__ float wsh[128][64];
    const int pb = b - 1024;
    const int brow = (pb & 63) * 64;
    const int p = pb >> 6, h = p / 3, which = p % 3;
    const float* W = (which == 0 ? wq : which == 1 ? wk : wv) + h * F * O;

#pragma unroll
    for (int i = 0; i < 8; i++) {
      int idx = t + i * 256, r = idx >> 5, c4 = idx & 31;
      *(float4*)&xs[r][c4 * 4] = *(const float4*)&x[(brow + r) * F + c4 * 4];
    }
#pragma unroll
    for (int i = 0; i < 8; i++) {
      int idx = t + i * 256, r = idx >> 4, c4 = idx & 15;
      *(float4*)&wsh[r][c4 * 4] = *(const float4*)&W[r * O + c4 * 4];
    }
    __syncthreads();

    const int r0 = (t >> 4) << 2, c0 = (t & 15) << 2;
    float acc[4][4] = {};
#pragma unroll 8
    for (int f = 0; f < F; f++) {
      float4 bb = *(float4*)&wsh[f][c0];
      float a0 = xs[r0 + 0][f], a1 = xs[r0 + 1][f];
      float a2 = xs[r0 + 2][f], a3 = xs[r0 + 3][f];
      acc[0][0] = fmaf(a0, bb.x, acc[0][0]); acc[0][1] = fmaf(a0, bb.y, acc[0][1]);
      acc[0][2] = fmaf(a0, bb.z, acc[0][2]); acc[0][3] = fmaf(a0, bb.w, acc[0][3]);
      acc[1][0] = fmaf(a1, bb.x, acc[1][0]); acc[1][1] = fmaf(a1, bb.y, acc[1][1]);
      acc[1][2] = fmaf(a1, bb.z, acc[1][2]); acc[1][3] = fmaf(a1, bb.w, acc[1][3]);
      acc[2][0] = fmaf(a2, bb.x, acc[2][0]); acc[2][1] = fmaf(a2, bb.y, acc[2][1]);
      acc[2][2] = fmaf(a2, bb.z, acc[2][2]); acc[2][3] = fmaf(a2, bb.w, acc[2][3]);
      acc[3][0] = fmaf(a3, bb.x, acc[3][0]); acc[3][1] = fmaf(a3, bb.y, acc[3][1]);
      acc[3][2] = fmaf(a3, bb.z, acc[3][2]); acc[3][3] = fmaf(a3, bb.w, acc[3][3]);
    }

    if (which == 0) {
      u16* dst = Q + h * N * O;
#pragma unroll
      for (int i = 0; i < 4; i++) {
        u16x4 v4 = { f2bf(acc[i][0] * QSCALE), f2bf(acc[i][1] * QSCALE),
                     f2bf(acc[i][2] * QSCALE), f2bf(acc[i][3] * QSCALE) };
        *(u16x4*)&dst[(brow + r0 + i) * O + c0] = v4;
      }
    } else if (which == 1) {
      u16* dst = K + h * N * O;
#pragma unroll
      for (int i = 0; i < 4; i++) {
        u16x4 v4 = { f2bf(acc[i][0]), f2bf(acc[i][1]), f2bf(acc[i][2]), f2bf(acc[i][3]) };
        *(u16x4*)&dst[(brow + r0 + i) * O + c0] = v4;
      }
    } else {
      u16* dst = Vt + h * O * N;  // transposed store: Vt[o][n]
#pragma unroll
      for (int j = 0; j < 4; j++) {
        u16x4 v4 = { f2bf(acc[0][j]), f2bf(acc[1][j]), f2bf(acc[2][j]), f2bf(acc[3][j]) };
        *(u16x4*)&dst[(c0 + j) * N + brow + r0] = v4;
      }
    }
  } else {
    // ---- mask: row_mask[n] = any(x[n][f] != 0) ----
    int n = (b - 1792) * 256 + t;
    const float4* xr = (const float4*)(x + n * F);
    float s = 0.f;
#pragma unroll
    for (int i = 0; i < F / 4; i++) {
      float4 v = xr[i];
      s += fabsf(v.x) + fabsf(v.y) + fabsf(v.z) + fabsf(v.w);
    }
    rmask[n] = (s != 0.f) ? 1.f : 0.f;
  }
}

// ---------------------------------------------------------------------------
// Fused masked attention, staged-LDS pipelined (R10-verified structure).
// grid (N/64, H, 2), block 512 = 8 waves = 4 row-groups x 2 column-halves.
// K AND V staged via global_load_lds (double-buffered, XOR-swizzled, #21);
// LDS = kv 64KB + pst 16KB = exactly 80KB -> 2 blocks/CU.
// R12 trims: leaky = fmaxf(s, 0.2s) (exact); row-sums via ones-MFMA
// (replaces 16 adds/iter + the final shfl-xor reduce; ones exact in bf16).
// Q pre-scaled so P = 2^(leaky(s)). MFMA 16x16x32 bf16,
// C/D row=(l>>4)*4+r, col=l&15 (m89).
// ---------------------------------------------------------------------------
__global__ __launch_bounds__(512) void attn_kernel(
    const u64* __restrict__ bits, const u16* __restrict__ Qg,
    const u16* __restrict__ Kg, const u16* __restrict__ Vtg,
    float* __restrict__ Opart, float* __restrict__ Spart) {
  __shared__ __align__(16) char kv[2][4][8192];   // [buf][K0,K1,V0,V1][64x128B]
  __shared__ __align__(16) u16 pst[8][16][64];    // per-wave P staging, swizzled

  const int tid = threadIdx.x;
  const int w = tid >> 6, l = tid & 63;
  const int lm = l & 15, lg = l >> 4;
  const int rg = w >> 1, hc = w & 1;     // row-group 0..3, column-half 0..1
  const int h = blockIdx.y;
  const int z = blockIdx.z;              // column slice 0..1 (2048 cols each)
  const int R0 = blockIdx.x * 64;
  const int WR0 = R0 + rg * 16;          // this wave's 16 Q-rows
  const int CB0 = z * 2048;              // this block's column base

  const char* Kb = (const char*)(Kg + h * N * O);    // 128B per key-row
  const char* Vb = (const char*)(Vtg + h * O * N);   // 8KB per o-row
  const u64* bblk = bits + (size_t)WR0 * NW;

  // staging geometry: lane fills LDS slot (row=w*8+(l>>3), col=(l&7)*16);
  // source is the INVERSE-swizzled global column (involution).
  const int srow = w * 8 + (l >> 3);                   // 0..63
  const int scol = ((l & 7) * 16) ^ ((srow & 7) << 4); // swizzled 16B chunk

  // Q fragments (held in regs): A[m=lm][k=lg*8+j]
  const u16* Qh = Qg + h * N * O;
  bf16x8 qa0 = *(const bf16x8*)&Qh[(WR0 + lm) * O + lg * 8];
  bf16x8 qa1 = *(const bf16x8*)&Qh[(WR0 + lm) * O + 32 + lg * 8];

  // all-ones bf16 B-fragment for the row-sum MFMA
  bf16x8 ones;
#pragma unroll
  for (int i = 0; i < 8; i++) ones[i] = (short)0x3F80;

  // pst addressing (byte offsets into this wave's 2KB slot), swizzled
  char* pbase = (char*)&pst[w][0][0];
  const char* prd0 = pbase + lm * 128 + ((lg * 16) ^ ((lm & 7) << 4));
  const char* prd1 = pbase + lm * 128 + ((64 + lg * 16) ^ ((lm & 7) << 4));

  f32x4 oacc[4];
  f32x4 lacc = {0.f, 0.f, 0.f, 0.f};     // row-sum accumulator (ones-MFMA)
#pragma unroll
  for (int i = 0; i < 4; i++) oacc[i] = (f32x4){0.f, 0.f, 0.f, 0.f};
  const f32x4 zero4 = {0.f, 0.f, 0.f, 0.f};

  auto STAGE = [&](int b, int t) {
    __builtin_amdgcn_global_load_lds(
        (const u32*)(Kb + (size_t)(CB0 + 0 * 1024 + t * 64 + srow) * 128 + scol),
        (u32*)&kv[b][0][w * 1024], 16, 0, 0);
    __builtin_amdgcn_global_load_lds(
        (const u32*)(Kb + (size_t)(CB0 + 1 * 1024 + t * 64 + srow) * 128 + scol),
        (u32*)&kv[b][1][w * 1024], 16, 0, 0);
    __builtin_amdgcn_global_load_lds(
        (const u32*)(Vb + (size_t)srow * (N * 2) + (CB0 + 0 * 1024 + t * 64) * 2 + scol),
        (u32*)&kv[b][2][w * 1024], 16, 0, 0);
    __builtin_amdgcn_global_load_lds(
        (const u32*)(Vb + (size_t)srow * (N * 2) + (CB0 + 1 * 1024 + t * 64) * 2 + scol),
        (u32*)&kv[b][3][w * 1024], 16, 0, 0);
  };

  STAGE(0, 0);
  __syncthreads();

  int b = 0;
#pragma unroll 1
  for (int t = 0; t < NT; ++t) {
    if (t + 1 < NT) STAGE(b ^ 1, t + 1);   // prefetch next tile (other buffer)

    const int widx = (CB0 >> 6) + hc * NT + t;   // 64-col word index

    // adjacency words (broadcast, L2-hot)
    u64 sh0 = bblk[(lg * 4 + 0) * NW + widx] >> lm;
    u64 sh1 = bblk[(lg * 4 + 1) * NW + widx] >> lm;
    u64 sh2 = bblk[(lg * 4 + 2) * NW + widx] >> lm;
    u64 sh3 = bblk[(lg * 4 + 3) * NW + widx] >> lm;

    // ---- S = Q K^T from staged K tile (swizzled reads) ----
    const char* Kt = &kv[b][hc][0];
    f32x4 sacc[4];
    __builtin_amdgcn_s_setprio(1);
#pragma unroll
    for (int tt = 0; tt < 4; tt++) {
      const int row = tt * 16 + lm;
      const int sw = (row & 7) << 4;
      bf16x8 kb0 = *(const bf16x8*)(Kt + row * 128 + ((lg * 16) ^ sw));
      bf16x8 kb1 = *(const bf16x8*)(Kt + row * 128 + ((lg * 16 + 64) ^ sw));
      f32x4 s0 = __builtin_amdgcn_mfma_f32_16x16x32_bf16(qa0, kb0, zero4, 0, 0, 0);
      sacc[tt] = __builtin_amdgcn_mfma_f32_16x16x32_bf16(qa1, kb1, s0, 0, 0, 0);
    }
    __builtin_amdgcn_s_setprio(0);

    // ---- P = adj ? 2^(max(s,0.2s)) : 0 ; stage bf16 P (swizzled) ----
#pragma unroll
    for (int tt = 0; tt < 4; tt++) {
#pragma unroll
      for (int r = 0; r < 4; r++) {
        u64 sh = (r == 0 ? sh0 : r == 1 ? sh1 : r == 2 ? sh2 : sh3);
        unsigned bit = (unsigned)(sh >> (tt * 16)) & 1u;
        float sv = sacc[tt][r];
        float lv = fmaxf(sv, 0.2f * sv);          // LeakyReLU, exact both signs
        float p = bit ? exp2_hw(lv) : 0.f;
        const int prow = lg * 4 + r;
        *(u16*)(pbase + prow * 128 +
                ((((tt * 16 + lm) * 2)) ^ ((prow & 7) << 4))) = f2bf(p);
      }
    }
    bf16x8 pa0 = *(const bf16x8*)prd0;
    bf16x8 pa1 = *(const bf16x8*)prd1;

    // ---- O += P V ; row-sums += P 1 (ones-MFMA) ----
    const char* Vt_ = &kv[b][2 + hc][0];
    __builtin_amdgcn_s_setprio(1);
#pragma unroll
    for (int ot = 0; ot < 4; ot++) {
      const int o = ot * 16 + lm;
      const int sw = (o & 7) << 4;
      bf16x8 vb0 = *(const bf16x8*)(Vt_ + o * 128 + ((lg * 16) ^ sw));
      bf16x8 vb1 = *(const bf16x8*)(Vt_ + o * 128 + ((lg * 16 + 64) ^ sw));
      oacc[ot] = __builtin_amdgcn_mfma_f32_16x16x32_bf16(pa0, vb0, oacc[ot], 0, 0, 0);
      oacc[ot] = __builtin_amdgcn_mfma_f32_16x16x32_bf16(pa1, vb1, oacc[ot], 0, 0, 0);
    }
    lacc = __builtin_amdgcn_mfma_f32_16x16x32_bf16(pa0, ones, lacc, 0, 0, 0);
    lacc = __builtin_amdgcn_mfma_f32_16x16x32_bf16(pa1, ones, lacc, 0, 0, 0);
    __builtin_amdgcn_s_setprio(0);

    __syncthreads();   // drains prefetch + protects buffer flip
    b ^= 1;
  }

  // ---- merge the 2 column-halves in LDS (Om2 aliases kv; barrier-safe).
  // Wave row-sums (lacc, replicated per col) parked raw in own pst slot. ----
  float (*Om2)[64][64] = (float (*)[64][64])&kv[0][0][0];  // 32KB
#pragma unroll
  for (int ot = 0; ot < 4; ot++)
#pragma unroll
    for (int r = 0; r < 4; r++)
      Om2[hc][rg * 16 + lg * 4 + r][ot * 16 + lm] = oacc[ot][r];
  if (lm == 0) {
    float* ps = (float*)pbase;
#pragma unroll
    for (int r = 0; r < 4; r++) ps[lg * 4 + r] = lacc[r];
  }
  __syncthreads();

  // ---- write partials: Opart[z][h][row][col], Spart[z][h][row] ----
  const int row = tid >> 3;          // 0..63
  const int c0 = (tid & 7) * 8;      // 0..56
  const int grow = R0 + row;
  float* op = &Opart[(((size_t)z * H + h) * N + grow) * O + c0];
#pragma unroll
  for (int j = 0; j < 8; j++)
    op[j] = Om2[0][row][c0 + j] + Om2[1][row][c0 + j];
  if ((tid & 7) == 0) {
    const int rg2 = row >> 4, ri = row & 15;
    float s0 = ((float*)&pst[rg2 * 2 + 0][0][0])[ri];
    float s1 = ((float*)&pst[rg2 * 2 + 1][0][0])[ri];
    Spart[((size_t)z * H + h) * N + grow] = s0 + s1;
  }
}

// ---------------------------------------------------------------------------
// Merge the 2 z-slices: out = relu((O0+O1)/(S0+S1)) * rowmask.
// ---------------------------------------------------------------------------
__global__ __launch_bounds__(256) void merge_kernel(
    const float* __restrict__ Opart, const float* __restrict__ Spart,
    const float* __restrict__ rowmask, float* __restrict__ out) {
  const int h = blockIdx.y;
  const int idx = blockIdx.x * 256 + threadIdx.x;
  const int row = idx >> 4, c0 = (idx & 15) * 4;
  float S = Spart[(size_t)h * N + row] + Spart[((size_t)H + h) * N + row];
  float inv = (S > 0.f) ? 1.f / S : 0.f;
  float rm = rowmask[row];
  const float4 o0 = *(const float4*)&Opart[((size_t)h * N + row) * O + c0];
  const float4 o1 = *(const float4*)&Opart[(((size_t)H + h) * N + row) * O + c0];
  float4 r;
  r.x = fmaxf((o0.x + o1.x) * inv, 0.f) * rm;
  r.y = fmaxf((o0.y + o1.y) * inv, 0.f) * rm;
  r.z = fmaxf((o0.z + o1.z) * inv, 0.f) * rm;
  r.w = fmaxf((o0.w + o1.w) * inv, 0.f) * rm;
  *(float4*)&out[(size_t)row * (H * O) + h * O + c0] = r;
}

extern "C" void kernel_launch(void* const* d_in, const int* in_sizes, int n_in,
                              void* d_out, int out_size, void* d_ws, size_t ws_size,
                              hipStream_t stream) {
  const float* x   = (const float*)d_in[0];  // h [1,4096,128]
  const float* adj = (const float*)d_in[1];  // a [1,4096,4096]
  const float* wv  = (const float*)d_in[2];  // kernel      -> V
  const float* wq  = (const float*)d_in[3];  // attn_kernel -> Q (f_self)
  const float* wk  = (const float*)d_in[4];  // attn_kernel2-> K (f_other)
  float* out = (float*)d_out;

  u16* Q  = (u16*)d_ws;                     // [4][4096][64] bf16  (2 MB)
  u16* K  = Q + H * N * O;                  // [4][4096][64] bf16  (2 MB)
  u16* Vt = K + H * N * O;                  // [4][64][4096] bf16  (2 MB)
  float* rmask = (float*)(Vt + H * N * O);  // [4096] f32 (16 KB)
  u64* bits = (u64*)(rmask + N);            // [4096][64] u64 (2 MB)
  float* Opart = (float*)(bits + (size_t)N * NW);  // [2][4][4096][64] f32 (8 MB)
  float* Spart = Opart + (size_t)2 * H * N * O;    // [2][4][4096] f32 (128 KB)

  prep_kernel<<<dim3(1808), 256, 0, stream>>>(x, adj, wv, wq, wk, Q, K, Vt, rmask, bits);
  attn_kernel<<<dim3(N / 64, H, 2), 512, 0, stream>>>(bits, Q, K, Vt, Opart, Spart);
  merge_kernel<<<dim3(N * O / 4 / 256, H), 256, 0, stream>>>(Opart, Spart, rmask, out);
}